// Round 9
// baseline (269.613 us; speedup 1.0000x reference)
//
#include <hip/hip_runtime.h>
#include <stdint.h>

// Problem constants
#define M_DIM 32768
#define N_DIM 1024
#define K_DIM 1024

using int32x4 = __attribute__((ext_vector_type(4))) int;
using int32x16 = __attribute__((ext_vector_type(16))) int;

__device__ __forceinline__ void gload_lds16(const void* g, void* l) {
  __builtin_amdgcn_global_load_lds(
      (const __attribute__((address_space(1))) void*)g,
      (__attribute__((address_space(3))) void*)l,
      16 /*bytes*/, 0 /*offset*/, 0 /*aux*/);
}

// ---------------- Kernel 1: fused weight-unpack + activation-quantize ----------------
// Blocks [0,512): unpack int4 weights -> int8 [N, K].
//   HARNESS NOTE: integer inputs arrive as int32 — weight_packed is 524288 int32
//   elements, ONE packed byte (0..255) per int32. Byte j of row r: low nibble ->
//   w[r][2j], high nibble -> w[r][2j+1]. sext4(v) = ((v&0xF)^8)-8.
// Blocks [512, 33280): quantize fp32 x -> int8: clip(rint(x*20), -127, 127).
__global__ __launch_bounds__(256) void prep_kernel(const float* __restrict__ x,
                                                   const int4* __restrict__ wp,
                                                   uint32_t* __restrict__ q,
                                                   uint2* __restrict__ w8) {
  const int bx = blockIdx.x;
  const int tid = threadIdx.x;
  if (bx < 512) {
    const int g = bx * 256 + tid;  // 4 packed bytes -> 8 int8
    const int4 p = wp[g];
    int w0 = ((p.x & 0xF) ^ 8) - 8;
    int w1 = (((p.x >> 4) & 0xF) ^ 8) - 8;
    int w2 = ((p.y & 0xF) ^ 8) - 8;
    int w3 = (((p.y >> 4) & 0xF) ^ 8) - 8;
    int w4 = ((p.z & 0xF) ^ 8) - 8;
    int w5 = (((p.z >> 4) & 0xF) ^ 8) - 8;
    int w6 = ((p.w & 0xF) ^ 8) - 8;
    int w7 = (((p.w >> 4) & 0xF) ^ 8) - 8;
    uint2 st;
    st.x = (uint32_t)(w0 & 0xFF) | ((uint32_t)(w1 & 0xFF) << 8) |
           ((uint32_t)(w2 & 0xFF) << 16) | ((uint32_t)(w3 & 0xFF) << 24);
    st.y = (uint32_t)(w4 & 0xFF) | ((uint32_t)(w5 & 0xFF) << 8) |
           ((uint32_t)(w6 & 0xFF) << 16) | ((uint32_t)(w7 & 0xFF) << 24);
    w8[g] = st;
  } else {
    const int g = (bx - 512) * 256 + tid;  // one float4 per thread
    const float4 v = ((const float4*)x)[g];
    int a0 = (int)rintf(fminf(fmaxf(v.x * 20.0f, -127.0f), 127.0f));
    int a1 = (int)rintf(fminf(fmaxf(v.y * 20.0f, -127.0f), 127.0f));
    int a2 = (int)rintf(fminf(fmaxf(v.z * 20.0f, -127.0f), 127.0f));
    int a3 = (int)rintf(fminf(fmaxf(v.w * 20.0f, -127.0f), 127.0f));
    q[g] = (uint32_t)(a0 & 0xFF) | ((uint32_t)(a1 & 0xFF) << 8) |
           ((uint32_t)(a2 & 0xFF) << 16) | ((uint32_t)(a3 & 0xFF) << 24);
  }
}

// ---------------- Kernel 2: int8 GEMM, 256x256 tile, all-wave staging ----------
// C[m][n] = (sum_k A[m][k]*W[n][k]) * 5e-4 + bias[n], f32 out.
// Block = 512 threads = 8 waves; wave w computes a 64x128 out sub-tile
// (m-quadrant wid>>1, n-half wid&1) as acc[2][4] of 32x32 mfma_i32_32x32x32_i8.
//
// WHY 256x256 (r4/r8 ledger): at 128x128 every schedule variant (producer
// wave / all-wave, 2/3/4 buffers, BK=64/128) landed 262-279 total — the
// per-window wall (~1.1us, r4 measured) dominates because per-window MFMA
// content is only 300-600 cyc. 256x256 gives 4x fewer block-windows (8192 vs
// 32768) and per-window per-SIMD MFMA rises to 2 waves x 16 x ~37 = 1184 cyc,
// comparable to the wall — plus 12 ds_reads/wave to overlap. 1 block/CU (96KB
// LDS) is accepted: unlike r4, the wall now has intra-block content under it.
//
// Staging = r8's proven discipline: per 256x64 K-tile, 32 wave-loads (16 A +
// 16 B); wave w owns 4 (A rows [32w,32w+32), B rows same). Distance-2
// prologue (8 in flight/wave), per-window: wait vmcnt(4) (my tile-kk loads
// landed, tile-kk+1's may fly — never drain), s_barrier, issue tile kk+2 into
// buf (kk+2)%3, then ds_read+MFMA tile kk. Identical path for all 8 waves.
// LDS chunk swizzle: LDS[r][c] = G[r][c ^ ((r>>1)&3)] (16B chunks, 4/row).
// Grid swizzle: 512 blocks; bx&7 = XCD owns m-tiles [16x,16x+16); the 4
// n-blocks sharing an m-panel are co-resident on that XCD -> A L2 reuse.
__global__ __launch_bounds__(512, 2) void gemm_kernel(const uint8_t* __restrict__ A,
                                                      const uint8_t* __restrict__ W,
                                                      const float* __restrict__ bias,
                                                      float* __restrict__ out) {
  __shared__ uint8_t sA[3][256 * 64];
  __shared__ uint8_t sB[3][256 * 64];

  const int tid = threadIdx.x;
  const int bx = blockIdx.x;
  const int xcd = bx & 7;
  const int tt = bx >> 3;                    // 0..63
  const int m0 = (xcd * 16 + (tt >> 2)) * 256;
  const int n0 = (tt & 3) * 256;

  const int lane = tid & 63;
  const int wid = tid >> 6;   // 0..7
  const int wm = wid >> 1;    // m-quadrant (64 rows each)
  const int wn = wid & 1;     // n-half (128 cols each)
  const int rl = lane & 31;   // row/col within 32-tile
  const int hl = lane >> 5;   // k-half selector

  // ---- staging role: wave wid owns A rows [32*wid,32*wid+32) and B same ----
  const uint8_t* gA[2];
  const uint8_t* gB[2];
  uint32_t lofs[2];
#pragma unroll
  for (int j = 0; j < 2; j++) {
    const int li = wid * 128 + j * 64 + lane;  // chunk id within 1024-chunk tile
    const int r = li >> 2, c = li & 3;         // row (64B = 4 chunks), slot
    const int cg = c ^ ((r >> 1) & 3);         // swizzled global 16B chunk
    gA[j] = A + (size_t)(m0 + r) * K_DIM + cg * 16;
    gB[j] = W + (size_t)(n0 + r) * K_DIM + cg * 16;
    lofs[j] = (uint32_t)li * 16;
  }

  // ---- compute role: fragment LDS byte offsets, swizzle-corrected ----
  uint32_t offA[2][2], offB[4][2];
#pragma unroll
  for (int mt = 0; mt < 2; mt++)
#pragma unroll
    for (int ks = 0; ks < 2; ks++) {
      const int rA = wm * 64 + mt * 32 + rl;
      const int ccA = (ks * 2 + hl) ^ ((rA >> 1) & 3);
      offA[mt][ks] = (uint32_t)(rA * 64 + ccA * 16);
    }
#pragma unroll
  for (int nt = 0; nt < 4; nt++)
#pragma unroll
    for (int ks = 0; ks < 2; ks++) {
      const int rB = wn * 128 + nt * 32 + rl;
      const int ccB = (ks * 2 + hl) ^ ((rB >> 1) & 3);
      offB[nt][ks] = (uint32_t)(rB * 64 + ccB * 16);
    }

  // Prologue: issue tile 0 -> buf0 and tile 1 -> buf1 (8 loads in flight/wave).
#pragma unroll
  for (int j = 0; j < 2; j++) {
    gload_lds16(gA[j], &sA[0][0] + lofs[j]);
    gload_lds16(gB[j], &sB[0][0] + lofs[j]);
  }
#pragma unroll
  for (int j = 0; j < 2; j++) {
    gload_lds16(gA[j] + 64, &sA[1][0] + lofs[j]);
    gload_lds16(gB[j] + 64, &sB[1][0] + lofs[j]);
  }

  int32x16 acc[2][4] = {};
#pragma unroll 1
  for (int kk = 0; kk < 16; kk++) {
    // My tile-kk loads complete (tile kk+1's 4 may stay in flight), then barrier.
    if (kk < 15) {
      asm volatile("s_waitcnt vmcnt(4)\n\ts_barrier" ::: "memory");
    } else {
      asm volatile("s_waitcnt vmcnt(0)\n\ts_barrier" ::: "memory");
    }
    if (kk < 14) {  // issue tile kk+2 into buf (kk+2)%3 (tile kk-1 fully consumed)
      const int off = (kk + 2) * 64;
      const uint32_t bo = (uint32_t)((kk + 2) % 3) * 16384;
#pragma unroll
      for (int j = 0; j < 2; j++) {
        gload_lds16(gA[j] + off, &sA[0][0] + bo + lofs[j]);
        gload_lds16(gB[j] + off, &sB[0][0] + bo + lofs[j]);
      }
    }
    const uint32_t cb = (uint32_t)(kk % 3) * 16384;
    const uint8_t* pA = &sA[0][0] + cb;
    const uint8_t* pB = &sB[0][0] + cb;
#pragma unroll
    for (int ks = 0; ks < 2; ks++) {
      int32x4 a0 = *(const int32x4*)(pA + offA[0][ks]);
      int32x4 a1 = *(const int32x4*)(pA + offA[1][ks]);
      int32x4 b0 = *(const int32x4*)(pB + offB[0][ks]);
      int32x4 b1 = *(const int32x4*)(pB + offB[1][ks]);
      int32x4 b2 = *(const int32x4*)(pB + offB[2][ks]);
      int32x4 b3 = *(const int32x4*)(pB + offB[3][ks]);
      acc[0][0] = __builtin_amdgcn_mfma_i32_32x32x32_i8(a0, b0, acc[0][0], 0, 0, 0);
      acc[0][1] = __builtin_amdgcn_mfma_i32_32x32x32_i8(a0, b1, acc[0][1], 0, 0, 0);
      acc[0][2] = __builtin_amdgcn_mfma_i32_32x32x32_i8(a0, b2, acc[0][2], 0, 0, 0);
      acc[0][3] = __builtin_amdgcn_mfma_i32_32x32x32_i8(a0, b3, acc[0][3], 0, 0, 0);
      acc[1][0] = __builtin_amdgcn_mfma_i32_32x32x32_i8(a1, b0, acc[1][0], 0, 0, 0);
      acc[1][1] = __builtin_amdgcn_mfma_i32_32x32x32_i8(a1, b1, acc[1][1], 0, 0, 0);
      acc[1][2] = __builtin_amdgcn_mfma_i32_32x32x32_i8(a1, b2, acc[1][2], 0, 0, 0);
      acc[1][3] = __builtin_amdgcn_mfma_i32_32x32x32_i8(a1, b3, acc[1][3], 0, 0, 0);
    }
  }

  // Epilogue. 32x32 C/D layout: col = lane&31, row = (reg&3) + 8*(reg>>2) + 4*(lane>>5).
  float bv[4];
#pragma unroll
  for (int nt = 0; nt < 4; nt++) bv[nt] = bias[n0 + wn * 128 + nt * 32 + rl];

#pragma unroll
  for (int mt = 0; mt < 2; mt++) {
#pragma unroll
    for (int nt = 0; nt < 4; nt++) {
      const int n_g = n0 + wn * 128 + nt * 32 + rl;
      const int mbase = m0 + wm * 64 + mt * 32 + 4 * hl;
#pragma unroll
      for (int reg = 0; reg < 16; reg++) {
        const int m_g = mbase + (reg & 3) + 8 * (reg >> 2);
        const float v = (float)acc[mt][nt][reg] * 0.0005f + bv[nt];
        // lanes 0..31 cover 32 consecutive n -> full 128B lines; write-once data.
        __builtin_nontemporal_store(v, &out[(size_t)m_g * N_DIM + n_g]);
      }
    }
  }
}

extern "C" void kernel_launch(void* const* d_in, const int* in_sizes, int n_in,
                              void* d_out, int out_size, void* d_ws, size_t ws_size,
                              hipStream_t stream) {
  const float* x = (const float*)d_in[0];
  const int4* wp = (const int4*)d_in[1];   // int32 per packed byte (harness int rule)
  const float* bias = (const float*)d_in[2];
  float* out = (float*)d_out;

  uint8_t* A8 = (uint8_t*)d_ws;                       // 32768*1024 int8 = 32 MiB
  uint8_t* W8 = A8 + (size_t)M_DIM * K_DIM;           // 1024*1024 int8 = 1 MiB

  // K1: fused unpack (512 blocks) + quantize (32768 blocks)
  prep_kernel<<<512 + (M_DIM * K_DIM) / (4 * 256), 256, 0, stream>>>(
      x, wp, (uint32_t*)A8, (uint2*)W8);
  // K2: GEMM. grid = (M/256)*(N/256) = 512 blocks, 512 threads (8 waves)
  gemm_kernel<<<(M_DIM / 256) * (N_DIM / 256), 512, 0, stream>>>(A8, W8, bias, out);
}